// Round 3
// baseline (533.649 us; speedup 1.0000x reference)
//
#include <hip/hip_runtime.h>
#include <stdint.h>

#define DIM 64
#define NC 8            // XCD-private histogram copies (blockIdx & 7 ~ XCD id)
#define SCAN_TILE 1024  // elements per scan block (256 threads x 4)

// ---- build kernels ------------------------------------------------------

// Per-XCD-copy degree histograms: copy-major layout deg8[c*n + i] so that the
// 8 copies of one node live on different cache lines (no cross-XCD ping-pong).
__global__ void count_kernel(const int* __restrict__ src, const int* __restrict__ dst,
                             int* __restrict__ outdeg8, int* __restrict__ indeg8,
                             int e, int n) {
    const int i = blockIdx.x * blockDim.x + threadIdx.x;
    const int c = blockIdx.x & (NC - 1);
    if (i < e) {
        atomicAdd(&outdeg8[c * n + src[i]], 1);
        atomicAdd(&indeg8[c * n + dst[i]], 1);
    }
}

// Merge copies: indeg[i] = sum_c indeg8[c][i]; suboff8[c][i] = prefix over c;
// dis[i] = rsqrt(sum_c outdeg8[c][i] + 1). All reads/writes coalesced per copy.
__global__ void __launch_bounds__(256)
merge_kernel(const int* __restrict__ indeg8, const int* __restrict__ outdeg8,
             int* __restrict__ indeg, int* __restrict__ suboff8,
             float* __restrict__ dis, int n) {
    const int i = blockIdx.x * blockDim.x + threadIdx.x;
    if (i >= n) return;
    int run = 0;
#pragma unroll
    for (int c = 0; c < NC; ++c) {
        suboff8[c * n + i] = run;
        run += indeg8[c * n + i];
    }
    indeg[i] = run;
    int od = 0;
#pragma unroll
    for (int c = 0; c < NC; ++c) od += outdeg8[c * n + i];
    dis[i] = rsqrtf((float)od + 1.0f);
}

// Phase 1: per-tile sums of indeg. 256 threads x 4 elements, coalesced int4.
__global__ void __launch_bounds__(256)
scan_partial(const int* __restrict__ indeg, int* __restrict__ partial, int n) {
    __shared__ int wsum[4];
    const int tid = threadIdx.x;
    const int base = blockIdx.x * SCAN_TILE + tid * 4;
    int s = 0;
    if (base + 3 < n) {
        int4 v = *(const int4*)(indeg + base);
        s = v.x + v.y + v.z + v.w;
    } else {
        for (int i = 0; i < 4; ++i) if (base + i < n) s += indeg[base + i];
    }
    for (int off = 32; off > 0; off >>= 1) s += __shfl_down(s, off, 64);
    const int lane = tid & 63, wid = tid >> 6;
    if (lane == 0) wsum[wid] = s;
    __syncthreads();
    if (tid == 0) partial[blockIdx.x] = wsum[0] + wsum[1] + wsum[2] + wsum[3];
}

// Phase 2: single-block exclusive scan of the (<=1024) tile sums; writes total.
__global__ void scan_blocksums(int* __restrict__ partial, int* __restrict__ offsets,
                               int nblocks, int n) {
    __shared__ int buf[1024];
    const int t = threadIdx.x;
    int v = (t < nblocks) ? partial[t] : 0;
    buf[t] = v;
    __syncthreads();
    for (int off = 1; off < 1024; off <<= 1) {
        int add = (t >= off) ? buf[t - off] : 0;
        __syncthreads();
        buf[t] += add;
        __syncthreads();
    }
    if (t < nblocks) partial[t] = buf[t] - v;   // exclusive prefix, in place
    if (t == 1023) offsets[n] = buf[1023];      // grand total
}

// Phase 3: per-tile exclusive scan + write offsets.
__global__ void __launch_bounds__(256)
scan_final(const int* __restrict__ indeg, const int* __restrict__ partial,
           int* __restrict__ offsets, int n) {
    __shared__ int wpre[4];
    const int tid = threadIdx.x;
    const int base = blockIdx.x * SCAN_TILE + tid * 4;
    int v0 = 0, v1 = 0, v2 = 0, v3 = 0;
    if (base + 3 < n) {
        int4 v = *(const int4*)(indeg + base);
        v0 = v.x; v1 = v.y; v2 = v.z; v3 = v.w;
    } else {
        if (base + 0 < n) v0 = indeg[base + 0];
        if (base + 1 < n) v1 = indeg[base + 1];
        if (base + 2 < n) v2 = indeg[base + 2];
        if (base + 3 < n) v3 = indeg[base + 3];
    }
    const int s = v0 + v1 + v2 + v3;
    int inc = s;
    const int lane = tid & 63, wid = tid >> 6;
    for (int off = 1; off < 64; off <<= 1) {
        int t = __shfl_up(inc, off, 64);
        if (lane >= off) inc += t;
    }
    if (lane == 63) wpre[wid] = inc;
    __syncthreads();
    if (tid == 0) {
        int r = 0;
        for (int w = 0; w < 4; ++w) { int t = wpre[w]; wpre[w] = r; r += t; }
    }
    __syncthreads();
    int run = (inc - s) + wpre[wid] + partial[blockIdx.x];
    if (base + 0 < n) { offsets[base + 0] = run; run += v0; }
    if (base + 1 < n) { offsets[base + 1] = run; run += v1; }
    if (base + 2 < n) { offsets[base + 2] = run; run += v2; }
    if (base + 3 < n) { offsets[base + 3] = run; run += v3; }
}

// CSR fill with XCD-private cursors. Slot = node base + this copy's sub-offset
// + private cursor. Edge->copy mapping MUST match count_kernel (same grid).
__global__ void fill_kernel(const int* __restrict__ src, const int* __restrict__ dst,
                            const float* __restrict__ ew, const float* __restrict__ dis,
                            const int* __restrict__ offsets, const int* __restrict__ suboff8,
                            int* __restrict__ cursor8, int2* __restrict__ csr,
                            int e, int n) {
    const int i = blockIdx.x * blockDim.x + threadIdx.x;
    const int c = blockIdx.x & (NC - 1);
    if (i < e) {
        int s = src[i], t = dst[i];
        float w = dis[s] * ew[i] * dis[t];
        int p = offsets[t] + suboff8[c * n + t] + atomicAdd(&cursor8[c * n + t], 1);
        csr[p] = make_int2(s, __float_as_int(w));
    }
}

// ---- propagation --------------------------------------------------------
// One wave (64 lanes) per node; lane = feature index. Edge loop unrolled x4
// so 4 independent 256B gathers are in flight per wave.
// mode 0: xstore = v; out  = 0.25*(xin + v)      (layer 1; xin == embedding)
// mode 1: xstore = v; out += 0.25*v              (layer 2)
// mode 2:              out += 0.25*v             (layer 3, no store)
__global__ void __launch_bounds__(256)
prop_kernel(const float* __restrict__ xin, float* __restrict__ xstore,
            float* __restrict__ out,
            const int* __restrict__ offsets, const int2* __restrict__ csr,
            const float* __restrict__ dis, int n, int mode) {
    const int lane = threadIdx.x & 63;
    const int node = blockIdx.x * (blockDim.x >> 6) + (threadIdx.x >> 6);
    if (node >= n) return;

    const int beg = offsets[node];
    const int end = offsets[node + 1];
    const float d = dis[node];
    const int o = node * DIM + lane;

    float acc = d * d * xin[o];  // self-loop: norm = dis[i]^2, weight 1
    int p = beg;
    for (; p + 4 <= end; p += 4) {
        int2 e0 = csr[p + 0];
        int2 e1 = csr[p + 1];
        int2 e2 = csr[p + 2];
        int2 e3 = csr[p + 3];
        float x0 = xin[e0.x * DIM + lane];
        float x1 = xin[e1.x * DIM + lane];
        float x2 = xin[e2.x * DIM + lane];
        float x3 = xin[e3.x * DIM + lane];
        acc = fmaf(__int_as_float(e0.y), x0, acc);
        acc = fmaf(__int_as_float(e1.y), x1, acc);
        acc = fmaf(__int_as_float(e2.y), x2, acc);
        acc = fmaf(__int_as_float(e3.y), x3, acc);
    }
    for (; p < end; ++p) {
        int2 e = csr[p];
        acc = fmaf(__int_as_float(e.y), xin[e.x * DIM + lane], acc);
    }

    if (mode != 2) xstore[o] = acc;
    if (mode == 0) out[o] = 0.25f * (xin[o] + acc);
    else           out[o] += 0.25f * acc;
}

// ---- launch -------------------------------------------------------------

extern "C" void kernel_launch(void* const* d_in, const int* in_sizes, int n_in,
                              void* d_out, int out_size, void* d_ws, size_t ws_size,
                              hipStream_t stream) {
    const float* emb = (const float*)d_in[0];   // [N, 64] fp32
    const float* ew  = (const float*)d_in[1];   // [E] fp32
    const int*   ei  = (const int*)d_in[2];     // [2, E] int32
    const int E = in_sizes[2] / 2;
    const int N = in_sizes[0] / DIM;
    const int* src = ei;        // edge_index[0] = source j
    const int* dst = ei + E;    // edge_index[1] = target i
    float* out = (float*)d_out;

    const int nscan = (N + SCAN_TILE - 1) / SCAN_TILE;  // <=1024 tiles supported

    // workspace layout
    char* w = (char*)d_ws;
    int* outdeg8 = (int*)w;  w += (size_t)NC * N * 4;   // |
    int* indeg8  = (int*)w;  w += (size_t)NC * N * 4;   // | contiguous: one memset
    int* cursor8 = (int*)w;  w += (size_t)NC * N * 4;   // |
    int* suboff8 = (int*)w;  w += (size_t)NC * N * 4;
    int* indeg   = (int*)w;  w += (size_t)N * 4;
    int* offsets = (int*)w;  w += (size_t)(N + 1) * 4;
    float* dis   = (float*)w; w += (size_t)N * 4;
    int* partial = (int*)w;  w += (size_t)1024 * 4;
    w = (char*)(((uintptr_t)w + 255) & ~(uintptr_t)255);
    int2* csr    = (int2*)w; w += (size_t)E * 8;
    w = (char*)(((uintptr_t)w + 255) & ~(uintptr_t)255);
    float* xa    = (float*)w; w += (size_t)N * DIM * 4;
    float* xb    = (float*)w; w += (size_t)N * DIM * 4;

    // zero outdeg8, indeg8, cursor8 (contiguous, 3*NC*N ints)
    hipMemsetAsync(outdeg8, 0, (size_t)3 * NC * N * 4, stream);

    const int TB = 256;
    const int egrid = (E + TB - 1) / TB;
    count_kernel<<<egrid, TB, 0, stream>>>(src, dst, outdeg8, indeg8, E, N);
    merge_kernel<<<(N + TB - 1) / TB, TB, 0, stream>>>(indeg8, outdeg8, indeg,
                                                       suboff8, dis, N);
    scan_partial<<<nscan, TB, 0, stream>>>(indeg, partial, N);
    scan_blocksums<<<1, 1024, 0, stream>>>(partial, offsets, nscan, N);
    scan_final<<<nscan, TB, 0, stream>>>(indeg, partial, offsets, N);
    fill_kernel<<<egrid, TB, 0, stream>>>(src, dst, ew, dis, offsets, suboff8,
                                          cursor8, csr, E, N);

    const int WPB = TB / 64;  // 4 nodes (waves) per block
    dim3 grid((N + WPB - 1) / WPB), block(TB);
    prop_kernel<<<grid, block, 0, stream>>>(emb, xa, out, offsets, csr, dis, N, 0);
    prop_kernel<<<grid, block, 0, stream>>>(xa, xb, out, offsets, csr, dis, N, 1);
    prop_kernel<<<grid, block, 0, stream>>>(xb, nullptr, out, offsets, csr, dis, N, 2);
}

// Round 4
// 465.295 us; speedup vs baseline: 1.1469x; 1.1469x over previous
//
#include <hip/hip_runtime.h>
#include <stdint.h>

#define DIM 64
#define SCAN_TILE 1024  // elements per scan block (256 threads x 4)

// ---- build kernels ------------------------------------------------------

// outdeg histogram (for normalization) + indeg histogram WITH RETURN:
// the returned old value is this edge's rank within its destination's CSR
// segment -> fill_kernel needs no atomics at all.
__global__ void count_kernel(const int* __restrict__ src, const int* __restrict__ dst,
                             int* __restrict__ outdeg, int* __restrict__ indeg,
                             int* __restrict__ rank, int e) {
    int i = blockIdx.x * blockDim.x + threadIdx.x;
    if (i < e) {
        atomicAdd(&outdeg[src[i]], 1);
        rank[i] = atomicAdd(&indeg[dst[i]], 1);
    }
}

// Phase 1: per-tile sums of indeg. 256 threads x 4 elements, coalesced int4.
__global__ void __launch_bounds__(256)
scan_partial(const int* __restrict__ indeg, int* __restrict__ partial, int n) {
    __shared__ int wsum[4];
    const int tid = threadIdx.x;
    const int base = blockIdx.x * SCAN_TILE + tid * 4;
    int s = 0;
    if (base + 3 < n) {
        int4 v = *(const int4*)(indeg + base);
        s = v.x + v.y + v.z + v.w;
    } else {
        for (int i = 0; i < 4; ++i) if (base + i < n) s += indeg[base + i];
    }
    for (int off = 32; off > 0; off >>= 1) s += __shfl_down(s, off, 64);
    const int lane = tid & 63, wid = tid >> 6;
    if (lane == 0) wsum[wid] = s;
    __syncthreads();
    if (tid == 0) partial[blockIdx.x] = wsum[0] + wsum[1] + wsum[2] + wsum[3];
}

// Phase 2: single-block exclusive scan of the (<=1024) tile sums; writes total.
__global__ void scan_blocksums(int* __restrict__ partial, int* __restrict__ offsets,
                               int nblocks, int n) {
    __shared__ int buf[1024];
    const int t = threadIdx.x;
    int v = (t < nblocks) ? partial[t] : 0;
    buf[t] = v;
    __syncthreads();
    for (int off = 1; off < 1024; off <<= 1) {
        int add = (t >= off) ? buf[t - off] : 0;
        __syncthreads();
        buf[t] += add;
        __syncthreads();
    }
    if (t < nblocks) partial[t] = buf[t] - v;   // exclusive prefix, in place
    if (t == 1023) offsets[n] = buf[1023];      // grand total
}

// Phase 3: per-tile exclusive scan + write offsets; fuses dis = rsqrt(outdeg+1)
// (each node visited exactly once here).
__global__ void __launch_bounds__(256)
scan_final(const int* __restrict__ indeg, const int* __restrict__ partial,
           int* __restrict__ offsets, const int* __restrict__ outdeg,
           float* __restrict__ dis, int n) {
    __shared__ int wpre[4];
    const int tid = threadIdx.x;
    const int base = blockIdx.x * SCAN_TILE + tid * 4;
    int v0 = 0, v1 = 0, v2 = 0, v3 = 0;
    if (base + 3 < n) {
        int4 v = *(const int4*)(indeg + base);
        v0 = v.x; v1 = v.y; v2 = v.z; v3 = v.w;
    } else {
        if (base + 0 < n) v0 = indeg[base + 0];
        if (base + 1 < n) v1 = indeg[base + 1];
        if (base + 2 < n) v2 = indeg[base + 2];
        if (base + 3 < n) v3 = indeg[base + 3];
    }
    const int s = v0 + v1 + v2 + v3;
    int inc = s;
    const int lane = tid & 63, wid = tid >> 6;
    for (int off = 1; off < 64; off <<= 1) {
        int t = __shfl_up(inc, off, 64);
        if (lane >= off) inc += t;
    }
    if (lane == 63) wpre[wid] = inc;
    __syncthreads();
    if (tid == 0) {
        int r = 0;
        for (int w = 0; w < 4; ++w) { int t = wpre[w]; wpre[w] = r; r += t; }
    }
    __syncthreads();
    int run = (inc - s) + wpre[wid] + partial[blockIdx.x];
    if (base + 0 < n) { offsets[base + 0] = run; run += v0; dis[base + 0] = rsqrtf((float)outdeg[base + 0] + 1.0f); }
    if (base + 1 < n) { offsets[base + 1] = run; run += v1; dis[base + 1] = rsqrtf((float)outdeg[base + 1] + 1.0f); }
    if (base + 2 < n) { offsets[base + 2] = run; run += v2; dis[base + 2] = rsqrtf((float)outdeg[base + 2] + 1.0f); }
    if (base + 3 < n) { offsets[base + 3] = run; run += v3; dis[base + 3] = rsqrtf((float)outdeg[base + 3] + 1.0f); }
}

// Atomic-free CSR fill: slot is fully determined by offsets[dst] + rank.
__global__ void fill_kernel(const int* __restrict__ src, const int* __restrict__ dst,
                            const float* __restrict__ ew, const float* __restrict__ dis,
                            const int* __restrict__ offsets, const int* __restrict__ rank,
                            int2* __restrict__ csr, int e) {
    int i = blockIdx.x * blockDim.x + threadIdx.x;
    if (i < e) {
        int s = src[i], t = dst[i];
        float w = dis[s] * ew[i] * dis[t];
        csr[offsets[t] + rank[i]] = make_int2(s, __float_as_int(w));
    }
}

// ---- propagation --------------------------------------------------------
// 4 nodes per wave: lane = (sub = quarter 0..3 -> node, fl = 0..15 -> float4
// chunk of the 64-dim row). One global_load_dwordx4 fetches a full 256B row
// per quarter-wave => 4 edges serviced per load instruction; x4 unroll keeps
// up to 16 independent gathers in flight per wave.
// mode 0: xstore = v; out  = 0.25*(xin + v)      (layer 1; xin == embedding)
// mode 1: xstore = v; out += 0.25*v              (layer 2)
// mode 2:              out += 0.25*v             (layer 3, no store)
__global__ void __launch_bounds__(256)
prop_kernel(const float* __restrict__ xin, float* __restrict__ xstore,
            float* __restrict__ out,
            const int* __restrict__ offsets, const int2* __restrict__ csr,
            const float* __restrict__ dis, int n, int mode) {
    const int lane = threadIdx.x & 63;
    const int fl  = lane & 15;   // float4 chunk within row
    const int sub = lane >> 4;   // quarter -> which node
    const int wave = blockIdx.x * (blockDim.x >> 6) + (threadIdx.x >> 6);
    const int node = wave * 4 + sub;
    if (node >= n) return;

    const float4* __restrict__ x4 = (const float4*)xin;
    const int beg = offsets[node];
    const int end = offsets[node + 1];
    const float d = dis[node];
    const int ro = node * 16 + fl;   // float4 index of this lane's chunk

    float4 self = x4[ro];
    const float dd = d * d;          // self-loop: norm = dis[i]^2, weight 1
    float4 acc = make_float4(dd * self.x, dd * self.y, dd * self.z, dd * self.w);

#define STEP(E, X) { float w_ = __int_as_float((E).y); \
    acc.x = fmaf(w_, (X).x, acc.x); acc.y = fmaf(w_, (X).y, acc.y); \
    acc.z = fmaf(w_, (X).z, acc.z); acc.w = fmaf(w_, (X).w, acc.w); }

    int p = beg;
    for (; p + 4 <= end; p += 4) {
        int2 e0 = csr[p + 0];
        int2 e1 = csr[p + 1];
        int2 e2 = csr[p + 2];
        int2 e3 = csr[p + 3];
        float4 x0 = x4[e0.x * 16 + fl];
        float4 x1 = x4[e1.x * 16 + fl];
        float4 x2 = x4[e2.x * 16 + fl];
        float4 x3 = x4[e3.x * 16 + fl];
        STEP(e0, x0) STEP(e1, x1) STEP(e2, x2) STEP(e3, x3)
    }
    for (; p < end; ++p) {
        int2 e = csr[p];
        float4 xv = x4[e.x * 16 + fl];
        STEP(e, xv)
    }
#undef STEP

    if (mode != 2) ((float4*)xstore)[ro] = acc;
    float4* o4 = (float4*)out;
    if (mode == 0) {
        o4[ro] = make_float4(0.25f * (self.x + acc.x), 0.25f * (self.y + acc.y),
                             0.25f * (self.z + acc.z), 0.25f * (self.w + acc.w));
    } else {
        float4 prev = o4[ro];
        o4[ro] = make_float4(fmaf(0.25f, acc.x, prev.x), fmaf(0.25f, acc.y, prev.y),
                             fmaf(0.25f, acc.z, prev.z), fmaf(0.25f, acc.w, prev.w));
    }
}

// ---- launch -------------------------------------------------------------

extern "C" void kernel_launch(void* const* d_in, const int* in_sizes, int n_in,
                              void* d_out, int out_size, void* d_ws, size_t ws_size,
                              hipStream_t stream) {
    const float* emb = (const float*)d_in[0];   // [N, 64] fp32
    const float* ew  = (const float*)d_in[1];   // [E] fp32
    const int*   ei  = (const int*)d_in[2];     // [2, E] int32
    const int E = in_sizes[2] / 2;
    const int N = in_sizes[0] / DIM;
    const int* src = ei;        // edge_index[0] = source j
    const int* dst = ei + E;    // edge_index[1] = target i
    float* out = (float*)d_out;

    const int nscan = (N + SCAN_TILE - 1) / SCAN_TILE;  // <=1024 tiles supported

    // workspace layout
    char* w = (char*)d_ws;
    int* outdeg  = (int*)w;  w += (size_t)N * 4;   // | contiguous: one memset
    int* indeg   = (int*)w;  w += (size_t)N * 4;   // |
    int* offsets = (int*)w;  w += (size_t)(N + 1) * 4;
    float* dis   = (float*)w; w += (size_t)N * 4;
    int* partial = (int*)w;  w += (size_t)1024 * 4;
    w = (char*)(((uintptr_t)w + 255) & ~(uintptr_t)255);
    int* rank    = (int*)w;  w += (size_t)E * 4;
    w = (char*)(((uintptr_t)w + 255) & ~(uintptr_t)255);
    int2* csr    = (int2*)w; w += (size_t)E * 8;
    w = (char*)(((uintptr_t)w + 255) & ~(uintptr_t)255);
    float* xa    = (float*)w; w += (size_t)N * DIM * 4;
    float* xb    = (float*)w; w += (size_t)N * DIM * 4;

    // zero outdeg + indeg (contiguous)
    hipMemsetAsync(outdeg, 0, (size_t)2 * N * 4, stream);

    const int TB = 256;
    const int egrid = (E + TB - 1) / TB;
    count_kernel<<<egrid, TB, 0, stream>>>(src, dst, outdeg, indeg, rank, E);
    scan_partial<<<nscan, TB, 0, stream>>>(indeg, partial, N);
    scan_blocksums<<<1, 1024, 0, stream>>>(partial, offsets, nscan, N);
    scan_final<<<nscan, TB, 0, stream>>>(indeg, partial, offsets, outdeg, dis, N);
    fill_kernel<<<egrid, TB, 0, stream>>>(src, dst, ew, dis, offsets, rank, csr, E);

    // 4 waves/block, 4 nodes/wave -> 16 nodes per block
    dim3 grid((N + 15) / 16), block(TB);
    prop_kernel<<<grid, block, 0, stream>>>(emb, xa, out, offsets, csr, dis, N, 0);
    prop_kernel<<<grid, block, 0, stream>>>(xa, xb, out, offsets, csr, dis, N, 1);
    prop_kernel<<<grid, block, 0, stream>>>(xb, nullptr, out, offsets, csr, dis, N, 2);
}

// Round 6
// 417.350 us; speedup vs baseline: 1.2787x; 1.1149x over previous
//
#include <hip/hip_runtime.h>
#include <stdint.h>

#define DIM 64
#define BINS 16672      // bins per range: 66.7 KB LDS -> 2 blocks/CU
#define NSLICE 32       // edge slices (partials = NSLICE*N ints = 12.8 MB)
#define SCAN_TILE 1024  // elements per scan block (256 threads x 4)

typedef float v4f __attribute__((ext_vector_type(4)));  // nontemporal-compatible

// ---- histogram without global atomics -----------------------------------
// grid = 2 * R * NSLICE blocks. kind 0: histogram dst (indeg) AND emit
// per-edge local rank (LDS atomic return). kind 1: histogram src (outdeg).
// Block (kind,r,s) streams edge slice s, bins keys in [r*BINS,(r+1)*BINS),
// writes its bin-range counts to partials[kind][s][bin] (no zeroing needed:
// every (s,bin) cell is written by exactly one block).
__global__ void __launch_bounds__(256)
hist_kernel(const int* __restrict__ src, const int* __restrict__ dst,
            int* __restrict__ partialsA, int* __restrict__ partialsB,
            int* __restrict__ lrank, int E, int N, int R, int Es) {
    __shared__ int h[BINS];
    const int b = blockIdx.x;
    const int kind = b / (R * NSLICE);
    const int rs = b % (R * NSLICE);
    const int r = rs / NSLICE, s = rs % NSLICE;
    const int base = r * BINS;
    const int hi = min(base + BINS, N);
    const int nb = hi - base;
    for (int j = threadIdx.x; j < nb; j += blockDim.x) h[j] = 0;
    __syncthreads();
    const int e0 = s * Es, e1 = min(e0 + Es, E);
    if (kind == 0) {
        for (int i = e0 + threadIdx.x; i < e1; i += blockDim.x) {
            int k = dst[i];
            if (k >= base && k < hi) lrank[i] = atomicAdd(&h[k - base], 1);
        }
    } else {
        for (int i = e0 + threadIdx.x; i < e1; i += blockDim.x) {
            int k = src[i];
            if (k >= base && k < hi) atomicAdd(&h[k - base], 1);
        }
    }
    __syncthreads();
    int* part = (kind ? partialsB : partialsA) + (size_t)s * N + base;
    for (int j = threadIdx.x; j < nb; j += blockDim.x) part[j] = h[j];
}

// Per node: exclusive scan of indeg partials over slices (in place ->
// sliceoff), total -> indeg; sum outdeg partials -> dis = rsqrt(od+1).
__global__ void __launch_bounds__(256)
merge_kernel(int* __restrict__ partialsA, const int* __restrict__ partialsB,
             int* __restrict__ indeg, float* __restrict__ dis, int N) {
    const int i = blockIdx.x * blockDim.x + threadIdx.x;
    if (i >= N) return;
    int run = 0;
#pragma unroll
    for (int s = 0; s < NSLICE; ++s) {
        int v = partialsA[(size_t)s * N + i];
        partialsA[(size_t)s * N + i] = run;  // exclusive prefix -> sliceoff
        run += v;
    }
    indeg[i] = run;
    int od = 0;
#pragma unroll
    for (int s = 0; s < NSLICE; ++s) od += partialsB[(size_t)s * N + i];
    dis[i] = rsqrtf((float)od + 1.0f);  // deg = outdeg + 1 (self loop)
}

// ---- node-offset scan (3 phases) ----------------------------------------

__global__ void __launch_bounds__(256)
scan_partial(const int* __restrict__ indeg, int* __restrict__ partial, int n) {
    __shared__ int wsum[4];
    const int tid = threadIdx.x;
    const int base = blockIdx.x * SCAN_TILE + tid * 4;
    int s = 0;
    if (base + 3 < n) {
        int4 v = *(const int4*)(indeg + base);
        s = v.x + v.y + v.z + v.w;
    } else {
        for (int i = 0; i < 4; ++i) if (base + i < n) s += indeg[base + i];
    }
    for (int off = 32; off > 0; off >>= 1) s += __shfl_down(s, off, 64);
    const int lane = tid & 63, wid = tid >> 6;
    if (lane == 0) wsum[wid] = s;
    __syncthreads();
    if (tid == 0) partial[blockIdx.x] = wsum[0] + wsum[1] + wsum[2] + wsum[3];
}

__global__ void scan_blocksums(int* __restrict__ partial, int* __restrict__ offsets,
                               int nblocks, int n) {
    __shared__ int buf[1024];
    const int t = threadIdx.x;
    int v = (t < nblocks) ? partial[t] : 0;
    buf[t] = v;
    __syncthreads();
    for (int off = 1; off < 1024; off <<= 1) {
        int add = (t >= off) ? buf[t - off] : 0;
        __syncthreads();
        buf[t] += add;
        __syncthreads();
    }
    if (t < nblocks) partial[t] = buf[t] - v;
    if (t == 1023) offsets[n] = buf[1023];
}

__global__ void __launch_bounds__(256)
scan_final(const int* __restrict__ indeg, const int* __restrict__ partial,
           int* __restrict__ offsets, int n) {
    __shared__ int wpre[4];
    const int tid = threadIdx.x;
    const int base = blockIdx.x * SCAN_TILE + tid * 4;
    int v0 = 0, v1 = 0, v2 = 0, v3 = 0;
    if (base + 3 < n) {
        int4 v = *(const int4*)(indeg + base);
        v0 = v.x; v1 = v.y; v2 = v.z; v3 = v.w;
    } else {
        if (base + 0 < n) v0 = indeg[base + 0];
        if (base + 1 < n) v1 = indeg[base + 1];
        if (base + 2 < n) v2 = indeg[base + 2];
        if (base + 3 < n) v3 = indeg[base + 3];
    }
    const int s = v0 + v1 + v2 + v3;
    int inc = s;
    const int lane = tid & 63, wid = tid >> 6;
    for (int off = 1; off < 64; off <<= 1) {
        int t = __shfl_up(inc, off, 64);
        if (lane >= off) inc += t;
    }
    if (lane == 63) wpre[wid] = inc;
    __syncthreads();
    if (tid == 0) {
        int r = 0;
        for (int w = 0; w < 4; ++w) { int t = wpre[w]; wpre[w] = r; r += t; }
    }
    __syncthreads();
    int run = (inc - s) + wpre[wid] + partial[blockIdx.x];
    if (base + 0 < n) { offsets[base + 0] = run; run += v0; }
    if (base + 1 < n) { offsets[base + 1] = run; run += v1; }
    if (base + 2 < n) { offsets[base + 2] = run; run += v2; }
    if (base + 3 < n) { offsets[base + 3] = run; run += v3; }
}

// Atomic-free CSR fill: slot = offsets[dst] + sliceoff[slice][dst] + lrank.
__global__ void fill_kernel(const int* __restrict__ src, const int* __restrict__ dst,
                            const float* __restrict__ ew, const float* __restrict__ dis,
                            const int* __restrict__ offsets, const int* __restrict__ sliceoff,
                            const int* __restrict__ lrank, int2* __restrict__ csr,
                            int E, int N, int Es) {
    const int i = blockIdx.x * blockDim.x + threadIdx.x;
    if (i < E) {
        const int s = i / Es;
        const int t = dst[i], sc = src[i];
        float w = dis[sc] * ew[i] * dis[t];
        int slot = offsets[t] + sliceoff[(size_t)s * N + t] + lrank[i];
        csr[slot] = make_int2(sc, __float_as_int(w));
    }
}

// ---- propagation --------------------------------------------------------
// 4 nodes per wave: lane = (sub = quarter -> node, fl -> float4 chunk of the
// 64-dim row). x8 unroll keeps up to 32 independent row-gathers in flight.
// mode 0: xstore = v; out  = 0.25*(xin + v)      (layer 1; xin == embedding)
// mode 1: xstore = v; out += 0.25*v              (layer 2)
// mode 2:              out += 0.25*v             (layer 3, no store)
__global__ void __launch_bounds__(256)
prop_kernel(const float* __restrict__ xin, float* __restrict__ xstore,
            float* __restrict__ out,
            const int* __restrict__ offsets, const int2* __restrict__ csr,
            const float* __restrict__ dis, int n, int mode) {
    const int lane = threadIdx.x & 63;
    const int fl  = lane & 15;
    const int sub = lane >> 4;
    const int wave = blockIdx.x * (blockDim.x >> 6) + (threadIdx.x >> 6);
    const int node = wave * 4 + sub;
    if (node >= n) return;

    const float4* __restrict__ x4 = (const float4*)xin;
    const int beg = offsets[node];
    const int end = offsets[node + 1];
    const float d = dis[node];
    const int ro = node * 16 + fl;

    float4 self = x4[ro];
    const float dd = d * d;
    float4 acc = make_float4(dd * self.x, dd * self.y, dd * self.z, dd * self.w);

#define STEP(E, X) { float w_ = __int_as_float((E).y); \
    acc.x = fmaf(w_, (X).x, acc.x); acc.y = fmaf(w_, (X).y, acc.y); \
    acc.z = fmaf(w_, (X).z, acc.z); acc.w = fmaf(w_, (X).w, acc.w); }

    int p = beg;
    for (; p + 8 <= end; p += 8) {
        int2 e0 = csr[p + 0], e1 = csr[p + 1], e2 = csr[p + 2], e3 = csr[p + 3];
        int2 e4 = csr[p + 4], e5 = csr[p + 5], e6 = csr[p + 6], e7 = csr[p + 7];
        float4 x0 = x4[e0.x * 16 + fl];
        float4 x1 = x4[e1.x * 16 + fl];
        float4 x2 = x4[e2.x * 16 + fl];
        float4 x3 = x4[e3.x * 16 + fl];
        float4 x5 = x4[e4.x * 16 + fl];
        float4 x6 = x4[e5.x * 16 + fl];
        float4 x7 = x4[e6.x * 16 + fl];
        float4 x8 = x4[e7.x * 16 + fl];
        STEP(e0, x0) STEP(e1, x1) STEP(e2, x2) STEP(e3, x3)
        STEP(e4, x5) STEP(e5, x6) STEP(e6, x7) STEP(e7, x8)
    }
    for (; p < end; ++p) {
        int2 e = csr[p];
        float4 xv = x4[e.x * 16 + fl];
        STEP(e, xv)
    }
#undef STEP

    if (mode != 2) {
        // streaming write: don't evict gather-hot x rows
        v4f av = { acc.x, acc.y, acc.z, acc.w };
        __builtin_nontemporal_store(av, (v4f*)xstore + ro);
    }
    float4* o4 = (float4*)out;
    if (mode == 0) {
        o4[ro] = make_float4(0.25f * (self.x + acc.x), 0.25f * (self.y + acc.y),
                             0.25f * (self.z + acc.z), 0.25f * (self.w + acc.w));
    } else {
        float4 prev = o4[ro];
        o4[ro] = make_float4(fmaf(0.25f, acc.x, prev.x), fmaf(0.25f, acc.y, prev.y),
                             fmaf(0.25f, acc.z, prev.z), fmaf(0.25f, acc.w, prev.w));
    }
}

// ---- launch -------------------------------------------------------------

extern "C" void kernel_launch(void* const* d_in, const int* in_sizes, int n_in,
                              void* d_out, int out_size, void* d_ws, size_t ws_size,
                              hipStream_t stream) {
    const float* emb = (const float*)d_in[0];   // [N, 64] fp32
    const float* ew  = (const float*)d_in[1];   // [E] fp32
    const int*   ei  = (const int*)d_in[2];     // [2, E] int32
    const int E = in_sizes[2] / 2;
    const int N = in_sizes[0] / DIM;
    const int* src = ei;        // edge_index[0] = source j
    const int* dst = ei + E;    // edge_index[1] = target i
    float* out = (float*)d_out;

    const int R  = (N + BINS - 1) / BINS;          // node ranges
    const int Es = (E + NSLICE - 1) / NSLICE;      // edges per slice
    const int nscan = (N + SCAN_TILE - 1) / SCAN_TILE;

    // workspace layout (~97 MB)
    char* w = (char*)d_ws;
    int* partialsA = (int*)w; w += (size_t)NSLICE * N * 4;  // indeg partials -> sliceoff
    int* partialsB = (int*)w; w += (size_t)NSLICE * N * 4;  // outdeg partials
    int* lrank   = (int*)w;  w += (size_t)E * 4;
    int* indeg   = (int*)w;  w += (size_t)N * 4;
    int* offsets = (int*)w;  w += (size_t)(N + 1) * 4;
    float* dis   = (float*)w; w += (size_t)N * 4;
    int* partial = (int*)w;  w += (size_t)1024 * 4;
    w = (char*)(((uintptr_t)w + 255) & ~(uintptr_t)255);
    int2* csr    = (int2*)w; w += (size_t)E * 8;
    w = (char*)(((uintptr_t)w + 255) & ~(uintptr_t)255);
    float* xa    = (float*)w; w += (size_t)N * DIM * 4;
    float* xb    = (float*)w; w += (size_t)N * DIM * 4;
    // no memsets: every intermediate cell is fully overwritten each call

    const int TB = 256;
    hist_kernel<<<2 * R * NSLICE, TB, 0, stream>>>(src, dst, partialsA, partialsB,
                                                   lrank, E, N, R, Es);
    merge_kernel<<<(N + TB - 1) / TB, TB, 0, stream>>>(partialsA, partialsB,
                                                       indeg, dis, N);
    scan_partial<<<nscan, TB, 0, stream>>>(indeg, partial, N);
    scan_blocksums<<<1, 1024, 0, stream>>>(partial, offsets, nscan, N);
    scan_final<<<nscan, TB, 0, stream>>>(indeg, partial, offsets, N);
    fill_kernel<<<(E + TB - 1) / TB, TB, 0, stream>>>(src, dst, ew, dis, offsets,
                                                      partialsA, lrank, csr, E, N, Es);

    // 4 waves/block, 4 nodes/wave -> 16 nodes per block
    dim3 grid((N + 15) / 16), block(TB);
    prop_kernel<<<grid, block, 0, stream>>>(emb, xa, out, offsets, csr, dis, N, 0);
    prop_kernel<<<grid, block, 0, stream>>>(xa, xb, out, offsets, csr, dis, N, 1);
    prop_kernel<<<grid, block, 0, stream>>>(xb, nullptr, out, offsets, csr, dis, N, 2);
}